// Round 10
// baseline (289.938 us; speedup 1.0000x reference)
//
#include <hip/hip_runtime.h>
#include <stdint.h>

typedef unsigned int  u32;
typedef unsigned short u16;
typedef __bf16 v8bf __attribute__((ext_vector_type(8)));
typedef float  v4f  __attribute__((ext_vector_type(4)));

#define N_INST 256
#define BATCH  128
#define IN_DIM 1024
#define L_DIM  512
#define M_TOT  (N_INST*BATCH)   // 32768
#define NSLICE 16               // 16 colslices (64 pcols each)

// Fragment-tiled layouts (u16 units). Region = 1 KB = 64 lanes x 16 B.
// A (xb): region = mblk*256 + kt*16 + g*2 + kk   (g=row-group 0..7)
//   lane(q,c): row = mblk*128 + g*16 + c, k = kt*64 + kk*32 + q*8
// B (wpk): region = cs*128 + kt*8 + j*2 + kk     (cs=colslice 0..15, j=0..3)
//   lane(q,c): packed col p = cs*64 + j*16 + c, k = kt*64 + kk*32 + q*8
//   bcol = p>>4 = cs*4+j (even=V, odd=U), l = (bcol>>1)*16 + c
// ws: [0,64MB) xb; [64MB,66MB) wpk; [66MB,68MB) partial [16][M_TOT]
#define XB_BYTES   ((size_t)M_TOT * IN_DIM * 2)
#define WPK_BYTES  ((size_t)1024 * IN_DIM * 2)

__device__ inline u32 f2bf_pk(float a, float b){
  u32 ua = __builtin_bit_cast(u32, a);
  u32 ub = __builtin_bit_cast(u32, b);
  ua = (ua + 0x7FFFu + ((ua >> 16) & 1u)) >> 16;
  ub = (ub + 0x7FFFu + ((ub >> 16) & 1u)) & 0xFFFF0000u;
  return ua | ub;
}

__device__ inline void gl2lds16(const u16* g, u16* l){
  __builtin_amdgcn_global_load_lds(
      (const __attribute__((address_space(1))) u32*)(g),
      (__attribute__((address_space(3))) u32*)(l), 16, 0, 0);
}

#define PREP_XBLKS 16384
__global__ void prep(const float* __restrict__ x, const float* __restrict__ v,
                     const float* __restrict__ u, u16* __restrict__ xb,
                     u16* __restrict__ wpk){
  const int b = blockIdx.x;
  if (b < PREP_XBLKS){
    int t = b * 256 + threadIdx.x;
    int r = t >> 6, l = t & 63;
    int kk = r & 1, i = (r >> 1) & 3, h = (r >> 3) & 1, kt = (r >> 4) & 15, mb = r >> 8;
    int q = l >> 4, c = l & 15;
    int row = mb*128 + h*64 + i*16 + c;
    int k0  = kt*64 + kk*32 + q*8;
    const float* src = x + (size_t)row * IN_DIM + k0;
    float4 a0 = *reinterpret_cast<const float4*>(src);
    float4 a1 = *reinterpret_cast<const float4*>(src + 4);
    uint4 out;
    out.x = f2bf_pk(a0.x, a0.y); out.y = f2bf_pk(a0.z, a0.w);
    out.z = f2bf_pk(a1.x, a1.y); out.w = f2bf_pk(a1.z, a1.w);
    *reinterpret_cast<uint4*>(xb + (size_t)r*512 + l*8) = out;
  } else {
    int t = (b - PREP_XBLKS) * 256 + threadIdx.x;   // 131072 threads
    int r = t >> 6, l = t & 63;
    int kk = r & 1, j = (r >> 1) & 3, kt = (r >> 3) & 15, cs = r >> 7;
    int q = l >> 4, c = l & 15;
    int bcol = cs*4 + j;
    const float* src = (bcol & 1) ? u : v;
    int lcol = (bcol >> 1)*16 + c;
    int k0 = kt*64 + kk*32 + q*8;
    u32 o[4];
#pragma unroll
    for (int ii = 0; ii < 4; ++ii){
      float a  = src[(size_t)(k0 + 2*ii    ) * L_DIM + lcol];
      float bb = src[(size_t)(k0 + 2*ii + 1) * L_DIM + lcol];
      o[ii] = f2bf_pk(a, bb);
    }
    *reinterpret_cast<uint4*>(wpk + (size_t)r*512 + l*8) = make_uint4(o[0], o[1], o[2], o[3]);
  }
}

// ---- gemm_score: 128 rows x 128 pcols, 4 waves (2m x 2n), A+B LDS, kk-ring-3 ----
// kk-granular buffers: 16 regions = 16 KB (A: rr=g 0..7; B: rr=8+csloc*4+j).
// Ring-3 = 48 KB -> 3 blocks/CU, 12 waves, 170 regs -> NO SPILL (R8's schedule,
// R4/R5's register budget). Per step: STAGE(s+2, 4 loads/wave) -> FRAGS(s) ->
// 16 MFMA -> vmcnt(4)+s_barrier (counted: newest stage in flight, s+1 confirmed).
// Stage roles are wave-uniform: waves 0,1 stage A (g 0..3 / 4..7), waves 2,3
// stage B (csloc 0 / 1) -> one base pointer per wave, compile-time it-offsets.

#define STAGE(SP, RB) { _Pragma("unroll") for (int it_ = 0; it_ < 4; ++it_)           \
    gl2lds16((SP) + it_*1024, &Ls[(RB) + dst0 + it_*512]); }

#define FRAGS(RB) {                                                                   \
  _Pragma("unroll") for (int gi_ = 0; gi_ < 4; ++gi_)                                 \
    afb[gi_] = *reinterpret_cast<const v8bf*>(&Ls[(RB) + ao0 + gi_*512]);             \
  _Pragma("unroll") for (int j_ = 0; j_ < 4; ++j_)                                    \
    bfb[j_] = *reinterpret_cast<const v8bf*>(&Ls[(RB) + bo0 + j_*512]); }

#define MFMA16 {                                                                      \
  __builtin_amdgcn_s_setprio(1);                                                      \
  _Pragma("unroll") for (int j_ = 0; j_ < 4; ++j_)                                    \
    _Pragma("unroll") for (int gi_ = 0; gi_ < 4; ++gi_)                               \
      acc[gi_][j_] = __builtin_amdgcn_mfma_f32_16x16x32_bf16(                         \
          afb[gi_], bfb[j_], acc[gi_][j_], 0, 0, 0);                                  \
  __builtin_amdgcn_s_setprio(0); }

#define BARC(N) {                                                                     \
  __builtin_amdgcn_sched_barrier(0);                                                  \
  asm volatile("s_waitcnt vmcnt(" #N ")" ::: "memory");                               \
  __builtin_amdgcn_s_barrier();                                                       \
  __builtin_amdgcn_sched_barrier(0); }

__launch_bounds__(256, 3)
__global__ void gemm_score(const u16* __restrict__ xb, const u16* __restrict__ wpk,
                           const float* __restrict__ w, float* __restrict__ partial){
  __shared__ __align__(16) u16 Ls[3*16*512];   // 48 KB: 3 ring buffers x 16 regions

  const int tid  = threadIdx.x;
  const u32 bid  = blockIdx.x;            // 0..2047
  // bid = hi*64 + csp*8 + lo : lo = XCD; all 8 csp of an M-panel share an XCD.
  const int lo  = bid & 7;
  const int csp = (bid >> 3) & 7;         // 128-pcol slice pair 0..7
  const int hi  = bid >> 6;               // 0..31
  const int mblk = lo*32 + hi;            // 0..255 (128 rows each)

  const int lane = tid & 63;
  const int wave = tid >> 6;              // 0..3
  const int q    = lane >> 4;
  const int c    = lane & 15;
  const int wm   = wave >> 1;             // 0..1: 64-row group
  const int wn   = wave & 1;              // 0..1: 64-pcol group

  // stage source base (role is wave-uniform): waves 0,1 -> A; waves 2,3 -> B.
  // A region (kk=0): mblk*256 + kt*16 + g*2 ; wave w covers g = w*4 + it.
  // B region (kk=0): (csp*2+csloc)*128 + kt*8 + j*2 ; wave 2+csloc covers j = it.
  const u16* sbase;
  u32 astep;                              // kt stride (u16)
  if (wave < 2){
    sbase = xb + ((size_t)mblk*256 + (size_t)wave*8)*512 + lane*8;
    astep = 16*512;
  } else {
    sbase = wpk + ((size_t)(csp*2 + (wave-2))*128)*512 + lane*8;
    astep = 8*512;
  }
  const u16* spA = sbase;                 // even-step (kk=0) chain
  const u16* spB = sbase + 512;           // odd-step  (kk=1) chain

  const u32 dst0 = (u32)(wave*4)*512;               // stage dest: rr = wave*4 + it
  const u32 ao0  = (u32)(wm*4)*512 + lane*8;        // A frag: rr = wm*4 + gi
  const u32 bo0  = (u32)(8 + wn*4)*512 + lane*8;    // B frag: rr = 8 + wn*4 + j

  v8bf afb[4];
  v8bf bfb[4];
  v4f  acc[4][4];
#pragma unroll
  for (int gi = 0; gi < 4; ++gi)
#pragma unroll
    for (int j = 0; j < 4; ++j)
      acc[gi][j] = (v4f){0.f, 0.f, 0.f, 0.f};

  u32 rb0 = 0, rb1 = 8192, rb2 = 16384;   // ring bases (u16), 16 KB apart

  STAGE(spA, rb0); spA += astep;          // step 0 (kt0,kk0)
  STAGE(spB, rb1); spB += astep;          // step 1 (kt0,kk1)
  BARC(4);                                // step 0 confirmed (step 1 in flight)

#pragma unroll 1
  for (int kt = 0; kt < 15; ++kt){
    STAGE(spA, rb2); spA += astep;        // stage step 2kt+2
    FRAGS(rb0);
    MFMA16;
    BARC(4);                              // step 2kt+1 (rb1) confirmed
    STAGE(spB, rb0); spB += astep;        // stage step 2kt+3 (rb0 reads done)
    FRAGS(rb1);
    MFMA16;
    BARC(4);                              // step 2kt+2 (rb2) confirmed
    { u32 t = rb0; rb0 = rb2; rb2 = rb1; rb1 = t; }  // (rb0,rb1,rb2)<-(rb2,rb0,rb1)
  }
  // tail kt=15: rb0 = step 30 (confirmed); rb1 = step 31 (needs drain)
  FRAGS(rb0);
  MFMA16;
  BARC(0);                                // only full drain, once
  FRAGS(rb1);
  MFMA16;

  // epilogue: wave owns rows [mblk*128 + wm*64, +64), cs = csp*2 + wn
  const int cs = csp*2 + wn;
  const float wl0 = w[cs*32 + c];
  const float wl1 = w[cs*32 + 16 + c];
  float* pout = partial + (size_t)cs * M_TOT + (size_t)mblk*128 + wm*64;

#pragma unroll
  for (int gi = 0; gi < 4; ++gi){
#pragma unroll
    for (int r = 0; r < 4; ++r){
      float t0 = 2.f / (1.f + __expf(-2.f * acc[gi][0][r])) - 1.f;
      float s0 = 1.f / (1.f + __expf(-acc[gi][1][r]));
      float t1 = 2.f / (1.f + __expf(-2.f * acc[gi][2][r])) - 1.f;
      float s1 = 1.f / (1.f + __expf(-acc[gi][3][r]));
      float v2 = t0*s0*wl0 + t1*s1*wl1;
      v2 += __shfl_xor(v2, 1, 64);
      v2 += __shfl_xor(v2, 2, 64);
      v2 += __shfl_xor(v2, 4, 64);
      v2 += __shfl_xor(v2, 8, 64);
      if (c == 0) pout[gi*16 + q*4 + r] = v2;   // slice-private rows
    }
  }
}

__global__ void softmax_inst(const float* __restrict__ partial, float* __restrict__ out){
  __shared__ float red[N_INST];
  const int b = blockIdx.x;
  const int n = threadIdx.x;
  float s = 0.f;
#pragma unroll
  for (int i = 0; i < NSLICE; ++i) s += partial[(size_t)i * M_TOT + n*BATCH + b];
  red[n] = s; __syncthreads();
  for (int st = N_INST/2; st > 0; st >>= 1){
    if (n < st) red[n] = fmaxf(red[n], red[n + st]);
    __syncthreads();
  }
  float mx = red[0]; __syncthreads();
  float e = __expf(s - mx);
  red[n] = e; __syncthreads();
  for (int st = N_INST/2; st > 0; st >>= 1){
    if (n < st) red[n] += red[n + st];
    __syncthreads();
  }
  out[n*BATCH + b] = e / red[0];
}

extern "C" void kernel_launch(void* const* d_in, const int* in_sizes, int n_in,
                              void* d_out, int out_size, void* d_ws, size_t ws_size,
                              hipStream_t stream) {
  const float* x = (const float*)d_in[0];
  const float* v = (const float*)d_in[1];
  const float* u = (const float*)d_in[2];
  const float* w = (const float*)d_in[3];
  u16*   xb      = (u16*)d_ws;
  u16*   wpk     = (u16*)((char*)d_ws + XB_BYTES);
  float* partial = (float*)((char*)d_ws + XB_BYTES + WPK_BYTES);
  float* out     = (float*)d_out;

  prep<<<dim3(PREP_XBLKS + 512), dim3(256), 0, stream>>>(x, v, u, xb, wpk);
  gemm_score<<<dim3(2048), dim3(256), 0, stream>>>(xb, wpk, w, partial);
  softmax_inst<<<dim3(BATCH), dim3(N_INST), 0, stream>>>(partial, out);
}